// Round 6
// baseline (434.618 us; speedup 1.0000x reference)
//
#include <hip/hip_runtime.h>

// 3-layer LSTM (B=8192, T=336, F=8, H=20) + FC(20->20 relu) + FC(20->1).
//
// Round 13 (on R12): EXCLUSIVE-CU, DUAL-TILE waves.
//  Census: 5 cells/lane x 10 trans x 8cy = 400cy/substep trans issue ->
//  ~2700cy/iter per compute wave. At 2 blocks/CU (6 waves on 4 SIMDs) two
//  waves share a SIMD -> pacing 5400cy + convoy = 7950cy/iter measured.
//  Fix: 32 batch rows/block (2 MFMA tiles/wave), 256 blocks = 1/CU, LDS
//  padded to 81.5KB so 2 blocks can't co-reside -> waves get EXCLUSIVE
//  SIMDs; the two tiles' independent chains give in-wave ILP that hides
//  trans/bpermute/MFMA latency. Same total work, same 86 barriers.
//  Kept: prescaled gates + register h_self via bpermute (R12), 4 ts/barrier
//  + hoisted ba reads + setprio (R11), lgkm-only barrier (R9), XOR swizzle
//  (R9), unit-major leftover tile (R10), LICM pin (R4).
//
// MFMA layouts (m89/m120-verified): A[m][k]: m=lane&15,k=(lane>>4)*8+j;
// B[k][n]: n=lane&15,k=(lane>>4)*8+j; D[m][n]: n=lane&15,m=(lane>>4)*4+reg.

#define T_LEN 336
#define NJ 85   // j=0..85; w0: group j (t=4j..4j+3, j<=83); w1: group j-1; w2: group j-2

typedef _Float16 f16;
typedef _Float16 f16x4 __attribute__((ext_vector_type(4)));
typedef _Float16 f16x8 __attribute__((ext_vector_type(8)));
typedef float f32x4 __attribute__((ext_vector_type(4)));
typedef int i32x2 __attribute__((ext_vector_type(2)));
typedef int i32x4 __attribute__((ext_vector_type(4)));

#define MFMA(a, b, c) __builtin_amdgcn_mfma_f32_16x16x32_f16((a), (b), (c), 0, 0, 0)

// 16B-slot XOR swizzle for 64-f16 (128B) rows
#define SWZ1(n, c) ((c) ^ (((n) & 7) << 3))

#define KS1 1.4426950408889634f   // log2(e)
#define KS2 2.8853900817779268f   // 2*log2(e)

// prescaled activations: y arrives as -KS1*x (sigm) / -KS2*x (tanh)
__device__ __forceinline__ float sigm_p(float y) {
  return __builtin_amdgcn_rcpf(1.0f + __builtin_amdgcn_exp2f(y));
}
__device__ __forceinline__ float tanh_p(float y) {
  return 2.0f * __builtin_amdgcn_rcpf(1.0f + __builtin_amdgcn_exp2f(y)) - 1.0f;
}
__device__ __forceinline__ float tanh_fast(float x) {   // raw arg (cell state)
  return 2.0f * __builtin_amdgcn_rcpf(1.0f + __builtin_amdgcn_exp2f(-KS2 * x)) - 1.0f;
}

// 5 in-lane cells; gate inputs arrive PRESCALED. Cell states passed by name.
#define CELLS5(DI, DF, DG, DO, DL, C0, C1, C2, C3, C4, HV, HL) {                            \
  { float i_=sigm_p((DI)[0]), f_=sigm_p((DF)[0]), g_=tanh_p((DG)[0]), o_=sigm_p((DO)[0]);   \
    C0 = f_*C0 + i_*g_; (HV)[0] = (f16)(o_*tanh_fast(C0)); }                                \
  { float i_=sigm_p((DI)[1]), f_=sigm_p((DF)[1]), g_=tanh_p((DG)[1]), o_=sigm_p((DO)[1]);   \
    C1 = f_*C1 + i_*g_; (HV)[1] = (f16)(o_*tanh_fast(C1)); }                                \
  { float i_=sigm_p((DI)[2]), f_=sigm_p((DF)[2]), g_=tanh_p((DG)[2]), o_=sigm_p((DO)[2]);   \
    C2 = f_*C2 + i_*g_; (HV)[2] = (f16)(o_*tanh_fast(C2)); }                                \
  { float i_=sigm_p((DI)[3]), f_=sigm_p((DF)[3]), g_=tanh_p((DG)[3]), o_=sigm_p((DO)[3]);   \
    C3 = f_*C3 + i_*g_; (HV)[3] = (f16)(o_*tanh_fast(C3)); }                                \
  { float i_=sigm_p((DL)[0]), f_=sigm_p((DL)[1]), g_=tanh_p((DL)[2]), o_=sigm_p((DL)[3]);   \
    C4 = f_*C4 + i_*g_; (HL) = (f16)(o_*tanh_fast(C4)); } }

// L1/L2 substep, REGISTER h_self: rebuild bb from HVS/HLS via bpermute.
// lane(n,q) wants bb k=8q..8q+7 of [h_self 20 | pad12]:
//  q0: h0..7; q1: h8..15; q2: h16..19 + x0-wt garbage; q3: x0-wt garbage.
#define MSTEP_REG(BA, PUB, HVS, HLS, C0, C1, C2, C3, C4) {                                  \
  i32x2 _lo = __builtin_bit_cast(i32x2, HVS);                                               \
  int _hlu = (int)(unsigned)__builtin_bit_cast(unsigned short, HLS);                        \
  int _b0 = __builtin_amdgcn_ds_bpermute(adrA, _lo.x);                                      \
  int _b1 = __builtin_amdgcn_ds_bpermute(adrA, _lo.y);                                      \
  int _b2 = __builtin_amdgcn_ds_bpermute(adrB, _lo.x);                                      \
  int _b3 = __builtin_amdgcn_ds_bpermute(adrB, _lo.y);                                      \
  int _hA = __builtin_amdgcn_ds_bpermute(adr0, _hlu);                                       \
  int _hB = __builtin_amdgcn_ds_bpermute(adr1, _hlu);                                       \
  int _hC = __builtin_amdgcn_ds_bpermute(adr2, _hlu);                                       \
  int _hD = __builtin_amdgcn_ds_bpermute(adr3, _hlu);                                       \
  int _w0 = (q < 2) ? _b0 : ((_hA & 0xffff) | (_hB << 16));                                 \
  int _w1 = (q < 2) ? _b1 : ((_hC & 0xffff) | (_hD << 16));                                 \
  i32x4 _bbi = { _w0, _w1, _b2, _b3 };                                                      \
  f16x8 bb = __builtin_bit_cast(f16x8, _bbi);                                               \
  f32x4 di = MFMA(Fb0, bb, MFMA(Fa0, (BA), Bi));                                            \
  f32x4 df = MFMA(Fb1, bb, MFMA(Fa1, (BA), Bf));                                            \
  f32x4 dg = MFMA(Fb2, bb, MFMA(Fa2, (BA), Bg));                                            \
  f32x4 dn = MFMA(Fb3, bb, MFMA(Fa3, (BA), Bo));                                            \
  f32x4 dl = MFMA(Fb4, bb, MFMA(Fa4, (BA), BL));                                            \
  f16x4 hv; f16 hl; CELLS5(di, df, dg, dn, dl, C0, C1, C2, C3, C4, hv, hl)                  \
  HVS = hv; HLS = hl;                                                                       \
  f16* dp_ = (PUB);                                                                         \
  if (dp_) { *(f16x4*)&dp_[n * 64 + SWZ1(n, q * 4)] = hv;                                   \
             dp_[n * 64 + SWZ1(n, 16 + q)] = hl; } }

// L0 substep (LDS ring, per-tile base ZB): read slot S [x 8|h0 20|pad4],
// write h0 into slot D (c8..27), publish into PUB (c0..19).
#define L0S(ZB, S, D, PUB, C0, C1, C2, C3, C4) {                                            \
  f16x8 _bv = *(const f16x8*)&(ZB)[(S) * 1024 + n * 64 + SWZ1(n, q * 8)];                   \
  f32x4 di = MFMA(Fa0, _bv, Bi), df = MFMA(Fa1, _bv, Bf), dg = MFMA(Fa2, _bv, Bg),          \
        dn = MFMA(Fa3, _bv, Bo), dl = MFMA(Fa4, _bv, BL);                                   \
  f16x4 hv; f16 hl; CELLS5(di, df, dg, dn, dl, C0, C1, C2, C3, C4, hv, hl)                  \
  *(f16x4*)&(ZB)[(D) * 1024 + n * 64 + SWZ1(n, 8 + q * 4)] = hv;                            \
  (ZB)[(D) * 1024 + n * 64 + SWZ1(n, 24 + q)] = hl;                                         \
  f16* dp_ = (PUB);                                                                         \
  *(f16x4*)&dp_[n * 64 + SWZ1(n, q * 4)] = hv;                                              \
  dp_[n * 64 + SWZ1(n, 16 + q)] = hl; }

__global__ __launch_bounds__(192, 1) void lstm3_ws_kernel(
    const float* __restrict__ x,
    const float* __restrict__ Wih0, const float* __restrict__ Whh0,
    const float* __restrict__ bih0, const float* __restrict__ bhh0,
    const float* __restrict__ Wih1, const float* __restrict__ Whh1,
    const float* __restrict__ bih1, const float* __restrict__ bhh1,
    const float* __restrict__ Wih2, const float* __restrict__ Whh2,
    const float* __restrict__ bih2, const float* __restrict__ bhh2,
    const float* __restrict__ fc1w, const float* __restrict__ fc1b,
    const float* __restrict__ fc2w, const float* __restrict__ fc2b,
    float* __restrict__ out)
{
  // [tile][slot]: slot s holds [x(t) 8|h0(t-1) 20|pad] rows (swizzled)
  __shared__ __align__(16) f16 zT0[2][4][1024];
  // [tile][parity][sub]: [h0 20|pad44]
  __shared__ __align__(16) f16 zT1[2][2][4][1024];
  // [tile][parity][sub]: [h1 20|pad12|h2fin 20|pad] ; [t][1][0] c32..51 = final h2
  __shared__ __align__(16) f16 zT2[2][2][4][1024];
  __shared__ __align__(16) float pbuf[128];         // fc2 partials (2 tiles)
  __shared__ __align__(16) f16 lpad[512];           // pad: 81.5KB -> 1 block/CU

  const int tid  = threadIdx.x;
  const int w    = tid >> 6;        // wave id = layer id
  const int lane = tid & 63;
  const int n = lane & 15;          // batch elem (N index)
  const int q = lane >> 4;          // quad

  if ((int)blockIdx.x < 0) lpad[0] = (f16)1.f;   // keep pad allocated

  // bpermute source-lane byte addresses (lane*4)
  const int adrA = 4 * (n + 32 * (q & 1));
  const int adrB = 4 * (n + 16 + 32 * (q & 1));
  const int adr0 = 4 * n, adr1 = 4 * (n + 16), adr2 = 4 * (n + 32), adr3 = 4 * (n + 48);

  // ---- zero z buffers (h(.)=0, c implicit 0, pads 0) ----
  {
    f16x8 zer;
#pragma unroll
    for (int j = 0; j < 8; ++j) zer[j] = (f16)0.f;
    for (int i = tid; i < 1024; i += 192) ((f16x8*)&zT0[0][0][0])[i] = zer;
    for (int i = tid; i < 2048; i += 192) ((f16x8*)&zT1[0][0][0][0])[i] = zer;
    for (int i = tid; i < 2048; i += 192) ((f16x8*)&zT2[0][0][0][0])[i] = zer;
  }
  __syncthreads();

  // ---- per-wave register-resident fragments (PRESCALED, shared by tiles) ----
  auto rowmap = [](int T, int m) { return T < 4 ? T * 20 + m : (m & 3) * 20 + 16 + (m >> 2); };
  auto gscale = [](int T, int m) {
    int g = (T < 4) ? T : (m & 3);
    return (g == 2) ? -KS2 : -KS1;
  };

  f16x8 Fa0{}, Fa1{}, Fa2{}, Fa3{}, Fa4{};   // k-chunk 0 (w0: full [x|h] K)
  f16x8 Fb0{}, Fb1{}, Fb2{}, Fb3{}, Fb4{};   // k-chunk 1 (h_self; unused w0)
  f32x4 Bi{}, Bf{}, Bg{}, Bo{}, BL{};
  // per-tile cell states + register h_self
  float cA0 = 0.f, cA1 = 0.f, cA2 = 0.f, cA3 = 0.f, cA4 = 0.f;
  float cB0 = 0.f, cB1 = 0.f, cB2 = 0.f, cB3 = 0.f, cB4 = 0.f;
  f16x4 hvA{}, hvB{};
  f16 hlA = (f16)0.f, hlB = (f16)0.f;

  if (w == 0) {
    auto gA0 = [&](int T) {
      int row = rowmap(T, n);
      float sc = gscale(T, n);
      f16x8 r;
#pragma unroll
      for (int j = 0; j < 8; ++j) {
        int k = q * 8 + j;
        float v = (k < 8) ? Wih0[row * 8 + k] : (k < 28 ? Whh0[row * 20 + k - 8] : 0.f);
        r[j] = (f16)(sc * v);
      }
      return r;
    };
    Fa0 = gA0(0); Fa1 = gA0(1); Fa2 = gA0(2); Fa3 = gA0(3); Fa4 = gA0(4);
    auto gB = [&](int T) {
      f32x4 r;
#pragma unroll
      for (int j = 0; j < 4; ++j) {
        int m = q * 4 + j;
        int row = rowmap(T, m);
        r[j] = gscale(T, m) * (bih0[row] + bhh0[row]);
      }
      return r;
    };
    Bi = gB(0); Bf = gB(1); Bg = gB(2); Bo = gB(3); BL = gB(4);
  } else {
    const float* Wi = (w == 1) ? Wih1 : Wih2;
    const float* Wh = (w == 1) ? Whh1 : Whh2;
    const float* bi = (w == 1) ? bih1 : bih2;
    const float* bh = (w == 1) ? bhh1 : bhh2;
    auto gA = [&](int T, int c) {
      int row = rowmap(T, n);
      float sc = gscale(T, n);
      const float* W = c ? Wh : Wi;
      f16x8 r;
#pragma unroll
      for (int j = 0; j < 8; ++j) {
        int k = q * 8 + j;
        r[j] = (f16)((k < 20) ? sc * W[row * 20 + k] : 0.f);
      }
      return r;
    };
    Fa0 = gA(0, 0); Fb0 = gA(0, 1);
    Fa1 = gA(1, 0); Fb1 = gA(1, 1);
    Fa2 = gA(2, 0); Fb2 = gA(2, 1);
    Fa3 = gA(3, 0); Fb3 = gA(3, 1);
    Fa4 = gA(4, 0); Fb4 = gA(4, 1);
    auto gB = [&](int T) {
      f32x4 r;
#pragma unroll
      for (int j = 0; j < 4; ++j) {
        int m = q * 4 + j;
        int row = rowmap(T, m);
        r[j] = gscale(T, m) * (bi[row] + bh[row]);
      }
      return r;
    };
    Bi = gB(0); Bf = gB(1); Bg = gB(2); Bo = gB(3); BL = gB(4);
  }

  // x prefetch (wave0): dwordx4 = pair of 2 timesteps; 2 tiles.
  const float* xb0 = x + (size_t)(blockIdx.x * 32 + n) * (T_LEN * 8) + 4 * q;
  const float* xb1 = xb0 + (size_t)16 * (T_LEN * 8);
  f32x4 xA0{}, xB0{}, xA1{}, xB1{};
  if (w == 0) {
    xA0 = *(const f32x4*)(xb0);       xB0 = *(const f32x4*)(xb0 + 16);
    xA1 = *(const f32x4*)(xb1);       xB1 = *(const f32x4*)(xb1 + 16);
  }

  // ---- main loop: 4 timesteps per barrier, 2 tiles per wave ----
#pragma unroll 1
  for (int j = 0; j <= NJ; ++j) {
    asm volatile("" ::: "memory");   // pin LDS traffic in-loop (R4 fix)
    __builtin_amdgcn_s_setprio(1);   // computing waves outrank barrier-parked
    const int wp = j & 1, rp = wp ^ 1;
    if (w == 0) {
      if (j <= 83) {
        // stage x group j (both tiles): pair A -> slots 0/1, pair B -> slots 2/3
        f16x4 xh;
        xh[0] = (f16)xA0[0]; xh[1] = (f16)xA0[1]; xh[2] = (f16)xA0[2]; xh[3] = (f16)xA0[3];
        *(f16x4*)&zT0[0][q >> 1][n * 64 + SWZ1(n, 4 * (q & 1))] = xh;
        xh[0] = (f16)xB0[0]; xh[1] = (f16)xB0[1]; xh[2] = (f16)xB0[2]; xh[3] = (f16)xB0[3];
        *(f16x4*)&zT0[0][2 + (q >> 1)][n * 64 + SWZ1(n, 4 * (q & 1))] = xh;
        xh[0] = (f16)xA1[0]; xh[1] = (f16)xA1[1]; xh[2] = (f16)xA1[2]; xh[3] = (f16)xA1[3];
        *(f16x4*)&zT0[1][q >> 1][n * 64 + SWZ1(n, 4 * (q & 1))] = xh;
        xh[0] = (f16)xB1[0]; xh[1] = (f16)xB1[1]; xh[2] = (f16)xB1[2]; xh[3] = (f16)xB1[3];
        *(f16x4*)&zT0[1][2 + (q >> 1)][n * 64 + SWZ1(n, 4 * (q & 1))] = xh;
        // prefetch group j+1 (one full iteration of slack)
        int g = (j + 1 > 83) ? 83 : j + 1;
        xA0 = *(const f32x4*)(xb0 + (size_t)(2 * g) * 16);
        xB0 = *(const f32x4*)(xb0 + (size_t)(2 * g + 1) * 16);
        xA1 = *(const f32x4*)(xb1 + (size_t)(2 * g) * 16);
        xB1 = *(const f32x4*)(xb1 + (size_t)(2 * g + 1) * 16);
        f16* p10 = &zT1[0][wp][0][0];
        f16* p11 = &zT1[1][wp][0][0];
        f16* z00 = &zT0[0][0][0];
        f16* z01 = &zT0[1][0][0];
        L0S(z00, 0, 1, p10 + 0 * 1024, cA0, cA1, cA2, cA3, cA4)   // t=4j   tile0
        L0S(z01, 0, 1, p11 + 0 * 1024, cB0, cB1, cB2, cB3, cB4)   // t=4j   tile1
        L0S(z00, 1, 2, p10 + 1 * 1024, cA0, cA1, cA2, cA3, cA4)
        L0S(z01, 1, 2, p11 + 1 * 1024, cB0, cB1, cB2, cB3, cB4)
        L0S(z00, 2, 3, p10 + 2 * 1024, cA0, cA1, cA2, cA3, cA4)
        L0S(z01, 2, 3, p11 + 2 * 1024, cB0, cB1, cB2, cB3, cB4)
        L0S(z00, 3, 0, p10 + 3 * 1024, cA0, cA1, cA2, cA3, cA4)
        L0S(z01, 3, 0, p11 + 3 * 1024, cB0, cB1, cB2, cB3, cB4)
      }
    } else if (w == 1) {
      if (j >= 1 && j <= 84) {
        // L1 group j-1: h_in = h0 (published last iter), h_self in registers
        f16* s10 = &zT1[0][rp][0][0];
        f16* s11 = &zT1[1][rp][0][0];
        f16x8 a00 = *(const f16x8*)&s10[0 * 1024 + n * 64 + SWZ1(n, q * 8)];
        f16x8 a01 = *(const f16x8*)&s10[1 * 1024 + n * 64 + SWZ1(n, q * 8)];
        f16x8 a02 = *(const f16x8*)&s10[2 * 1024 + n * 64 + SWZ1(n, q * 8)];
        f16x8 a03 = *(const f16x8*)&s10[3 * 1024 + n * 64 + SWZ1(n, q * 8)];
        f16x8 a10 = *(const f16x8*)&s11[0 * 1024 + n * 64 + SWZ1(n, q * 8)];
        f16x8 a11 = *(const f16x8*)&s11[1 * 1024 + n * 64 + SWZ1(n, q * 8)];
        f16x8 a12 = *(const f16x8*)&s11[2 * 1024 + n * 64 + SWZ1(n, q * 8)];
        f16x8 a13 = *(const f16x8*)&s11[3 * 1024 + n * 64 + SWZ1(n, q * 8)];
        f16* p20 = &zT2[0][wp][0][0];
        f16* p21 = &zT2[1][wp][0][0];
        MSTEP_REG(a00, p20 + 0 * 1024, hvA, hlA, cA0, cA1, cA2, cA3, cA4)
        MSTEP_REG(a10, p21 + 0 * 1024, hvB, hlB, cB0, cB1, cB2, cB3, cB4)
        MSTEP_REG(a01, p20 + 1 * 1024, hvA, hlA, cA0, cA1, cA2, cA3, cA4)
        MSTEP_REG(a11, p21 + 1 * 1024, hvB, hlB, cB0, cB1, cB2, cB3, cB4)
        MSTEP_REG(a02, p20 + 2 * 1024, hvA, hlA, cA0, cA1, cA2, cA3, cA4)
        MSTEP_REG(a12, p21 + 2 * 1024, hvB, hlB, cB0, cB1, cB2, cB3, cB4)
        MSTEP_REG(a03, p20 + 3 * 1024, hvA, hlA, cA0, cA1, cA2, cA3, cA4)
        MSTEP_REG(a13, p21 + 3 * 1024, hvB, hlB, cB0, cB1, cB2, cB3, cB4)
      }
    } else {
      if (j >= 2) {
        // L2 group j-2: h_in = h1, h_self in registers; no publishes
        f16* s20 = &zT2[0][rp][0][0];
        f16* s21 = &zT2[1][rp][0][0];
        f16x8 a00 = *(const f16x8*)&s20[0 * 1024 + n * 64 + SWZ1(n, q * 8)];
        f16x8 a01 = *(const f16x8*)&s20[1 * 1024 + n * 64 + SWZ1(n, q * 8)];
        f16x8 a02 = *(const f16x8*)&s20[2 * 1024 + n * 64 + SWZ1(n, q * 8)];
        f16x8 a03 = *(const f16x8*)&s20[3 * 1024 + n * 64 + SWZ1(n, q * 8)];
        f16x8 a10 = *(const f16x8*)&s21[0 * 1024 + n * 64 + SWZ1(n, q * 8)];
        f16x8 a11 = *(const f16x8*)&s21[1 * 1024 + n * 64 + SWZ1(n, q * 8)];
        f16x8 a12 = *(const f16x8*)&s21[2 * 1024 + n * 64 + SWZ1(n, q * 8)];
        f16x8 a13 = *(const f16x8*)&s21[3 * 1024 + n * 64 + SWZ1(n, q * 8)];
        MSTEP_REG(a00, (f16*)nullptr, hvA, hlA, cA0, cA1, cA2, cA3, cA4)
        MSTEP_REG(a10, (f16*)nullptr, hvB, hlB, cB0, cB1, cB2, cB3, cB4)
        MSTEP_REG(a01, (f16*)nullptr, hvA, hlA, cA0, cA1, cA2, cA3, cA4)
        MSTEP_REG(a11, (f16*)nullptr, hvB, hlB, cB0, cB1, cB2, cB3, cB4)
        MSTEP_REG(a02, (f16*)nullptr, hvA, hlA, cA0, cA1, cA2, cA3, cA4)
        MSTEP_REG(a12, (f16*)nullptr, hvB, hlB, cB0, cB1, cB2, cB3, cB4)
        MSTEP_REG(a03, (f16*)nullptr, hvA, hlA, cA0, cA1, cA2, cA3, cA4)
        MSTEP_REG(a13, (f16*)nullptr, hvB, hlB, cB0, cB1, cB2, cB3, cB4)
      }
    }
    __builtin_amdgcn_s_setprio(0);
    // LDS-only barrier: cross-wave handoff needs lgkmcnt(0), NOT vmcnt(0) —
    // wave0's in-flight x loads stay outstanding across it (R9 fix).
    asm volatile("s_waitcnt lgkmcnt(0)\n\ts_barrier" ::: "memory");
  }

  // ---- FC head (wave2): final h2(335) in hvA/hlA (tile0), hvB/hlB (tile1).
  if (w == 2) {
    *(f16x4*)&zT2[0][1][0][n * 64 + SWZ1(n, 32 + q * 4)] = hvA;
    zT2[0][1][0][n * 64 + SWZ1(n, 48 + q)] = hlA;
    *(f16x4*)&zT2[1][1][0][n * 64 + SWZ1(n, 32 + q * 4)] = hvB;
    zT2[1][1][0][n * 64 + SWZ1(n, 48 + q)] = hlB;
    asm volatile("s_waitcnt lgkmcnt(0)" ::: "memory");
#pragma unroll
    for (int u = 0; u < 2; ++u) {
      const f16* hb = u ? &zT2[1][1][0][0] : &zT2[0][1][0][0];
      f16x4 hv0 = *(const f16x4*)&hb[n * 64 + SWZ1(n, 32)];
      f16x4 hv1 = *(const f16x4*)&hb[n * 64 + SWZ1(n, 36)];
      f16x4 hv2 = *(const f16x4*)&hb[n * 64 + SWZ1(n, 40)];
      f16x4 hv3 = *(const f16x4*)&hb[n * 64 + SWZ1(n, 44)];
      f16x4 hv4 = *(const f16x4*)&hb[n * 64 + SWZ1(n, 48)];
      float p = 0.f;
#pragma unroll
      for (int i = 0; i < 5; ++i) {
        int d = q * 5 + i;
        const float* wr = fc1w + d * 20;
        float s = fc1b[d]
          + wr[0]  * (float)hv0[0] + wr[1]  * (float)hv0[1] + wr[2]  * (float)hv0[2] + wr[3]  * (float)hv0[3]
          + wr[4]  * (float)hv1[0] + wr[5]  * (float)hv1[1] + wr[6]  * (float)hv1[2] + wr[7]  * (float)hv1[3]
          + wr[8]  * (float)hv2[0] + wr[9]  * (float)hv2[1] + wr[10] * (float)hv2[2] + wr[11] * (float)hv2[3]
          + wr[12] * (float)hv3[0] + wr[13] * (float)hv3[1] + wr[14] * (float)hv3[2] + wr[15] * (float)hv3[3]
          + wr[16] * (float)hv4[0] + wr[17] * (float)hv4[1] + wr[18] * (float)hv4[2] + wr[19] * (float)hv4[3];
        p += fc2w[d] * fmaxf(s, 0.f);
      }
      pbuf[u * 64 + n * 4 + q] = p;          // wave-internal, in-order
      if (q == 0) {
        f32x4 pv = *(const f32x4*)&pbuf[u * 64 + n * 4];
        out[blockIdx.x * 32 + u * 16 + n] = pv[0] + pv[1] + pv[2] + pv[3] + fc2b[0];
      }
    }
  }
}

extern "C" void kernel_launch(void* const* d_in, const int* in_sizes, int n_in,
                              void* d_out, int out_size, void* d_ws, size_t ws_size,
                              hipStream_t stream) {
  const float* x    = (const float*)d_in[0];
  const float* Wih0 = (const float*)d_in[1];
  const float* Whh0 = (const float*)d_in[2];
  const float* bih0 = (const float*)d_in[3];
  const float* bhh0 = (const float*)d_in[4];
  const float* Wih1 = (const float*)d_in[5];
  const float* Whh1 = (const float*)d_in[6];
  const float* bih1 = (const float*)d_in[7];
  const float* bhh1 = (const float*)d_in[8];
  const float* Wih2 = (const float*)d_in[9];
  const float* Whh2 = (const float*)d_in[10];
  const float* bih2 = (const float*)d_in[11];
  const float* bhh2 = (const float*)d_in[12];
  const float* fc1w = (const float*)d_in[13];
  const float* fc1b = (const float*)d_in[14];
  const float* fc2w = (const float*)d_in[15];
  const float* fc2b = (const float*)d_in[16];
  float* out = (float*)d_out;

  hipLaunchKernelGGL(lstm3_ws_kernel, dim3(8192 / 32), dim3(192), 0, stream,
                     x, Wih0, Whh0, bih0, bhh0,
                     Wih1, Whh1, bih1, bhh1,
                     Wih2, Whh2, bih2, bhh2,
                     fc1w, fc1b, fc2w, fc2b, out);
}

// Round 7
// 386.181 us; speedup vs baseline: 1.1254x; 1.1254x over previous
//
#include <hip/hip_runtime.h>

// 3-layer LSTM (B=8192, T=336, F=8, H=20) + FC(20->20 relu) + FC(20->1).
//
// Round 14 = R12 (284.9us, best) + 8 TIMESTEPS PER BARRIER, SAME LDS SIZE.
//  R13 lesson: 2 blocks/CU co-residency is the latency-hiding mechanism
//  (cross-block overlap fills barrier convoys); never break it. The naive
//  8-slot buffers (80KB) would -> 1 block/CU, so substeps are PACKED TWO
//  PER 64-f16 ROW (col-halves 0/32, R10's proven layout):
//   zT0 [4][1024]: row r = [x(2r) 8|h0(2r-1) 20|pad | x(2r+1)|h0(2r)|pad]
//   zT1/zT2 [2][4][1024]: rowset r = h published for substeps 2r,2r+1.
//  LDS stays ~41KB -> 2 blocks/CU. Barriers 86 -> 44.
//  Kept: prescaled gates + register h_self via bpermute (R12), hoisted h_in
//  reads + setprio (R11), lgkm-only barrier (R9), XOR swizzle (R9, same
//  formula both sides; bijective per row), unit-major leftover tile (R10),
//  LICM pin (R4).
//
// MFMA layouts (m89/m120-verified): A[m][k]: m=lane&15,k=(lane>>4)*8+j;
// B[k][n]: n=lane&15,k=(lane>>4)*8+j; D[m][n]: n=lane&15,m=(lane>>4)*4+reg.

#define T_LEN 336
#define NJ 43   // j=0..43; w0: group j (t=8j..8j+7, j<=41); w1: group j-1; w2: group j-2

typedef _Float16 f16;
typedef _Float16 f16x4 __attribute__((ext_vector_type(4)));
typedef _Float16 f16x8 __attribute__((ext_vector_type(8)));
typedef float f32x4 __attribute__((ext_vector_type(4)));
typedef int i32x2 __attribute__((ext_vector_type(2)));
typedef int i32x4 __attribute__((ext_vector_type(4)));

#define MFMA(a, b, c) __builtin_amdgcn_mfma_f32_16x16x32_f16((a), (b), (c), 0, 0, 0)

// 16B-slot XOR swizzle for 64-f16 (128B) rows
#define SWZ1(n, c) ((c) ^ (((n) & 7) << 3))

#define KS1 1.4426950408889634f   // log2(e)
#define KS2 2.8853900817779268f   // 2*log2(e)

// prescaled activations: y arrives as -KS1*x (sigm) / -KS2*x (tanh)
__device__ __forceinline__ float sigm_p(float y) {
  return __builtin_amdgcn_rcpf(1.0f + __builtin_amdgcn_exp2f(y));
}
__device__ __forceinline__ float tanh_p(float y) {
  return 2.0f * __builtin_amdgcn_rcpf(1.0f + __builtin_amdgcn_exp2f(y)) - 1.0f;
}
__device__ __forceinline__ float tanh_fast(float x) {   // raw arg (cell state)
  return 2.0f * __builtin_amdgcn_rcpf(1.0f + __builtin_amdgcn_exp2f(-KS2 * x)) - 1.0f;
}

// 5 in-lane cells; gate inputs arrive PRESCALED (see gA/gB loaders).
#define CELLS5(DI, DF, DG, DO, DL, HV, HL) {                                                \
  { float i_=sigm_p((DI)[0]), f_=sigm_p((DF)[0]), g_=tanh_p((DG)[0]), o_=sigm_p((DO)[0]);   \
    c0 = f_*c0 + i_*g_; (HV)[0] = (f16)(o_*tanh_fast(c0)); }                                \
  { float i_=sigm_p((DI)[1]), f_=sigm_p((DF)[1]), g_=tanh_p((DG)[1]), o_=sigm_p((DO)[1]);   \
    c1 = f_*c1 + i_*g_; (HV)[1] = (f16)(o_*tanh_fast(c1)); }                                \
  { float i_=sigm_p((DI)[2]), f_=sigm_p((DF)[2]), g_=tanh_p((DG)[2]), o_=sigm_p((DO)[2]);   \
    c2 = f_*c2 + i_*g_; (HV)[2] = (f16)(o_*tanh_fast(c2)); }                                \
  { float i_=sigm_p((DI)[3]), f_=sigm_p((DF)[3]), g_=tanh_p((DG)[3]), o_=sigm_p((DO)[3]);   \
    c3 = f_*c3 + i_*g_; (HV)[3] = (f16)(o_*tanh_fast(c3)); }                                \
  { float i_=sigm_p((DL)[0]), f_=sigm_p((DL)[1]), g_=tanh_p((DL)[2]), o_=sigm_p((DL)[3]);   \
    cL = f_*cL + i_*g_; (HL) = (f16)(o_*tanh_fast(cL)); } }

// L1/L2 substep, REGISTER h_self: rebuild bb from hvS/hlS via bpermute.
// lane(n,q) wants bb k=8q..8q+7 of [h_self 20 | pad12]:
//  q0: h0..7; q1: h8..15; q2: h16..19 + x0-wt garbage; q3: x0-wt garbage.
// Publishes hv/hl into PUB at col-base PC (0 or 32) when PUB != nullptr.
#define MSTEP_REG(BA, PUB, PC) {                                                            \
  i32x2 _lo = __builtin_bit_cast(i32x2, hvS);                                               \
  int _hlu = (int)(unsigned)__builtin_bit_cast(unsigned short, hlS);                        \
  int _b0 = __builtin_amdgcn_ds_bpermute(adrA, _lo.x);                                      \
  int _b1 = __builtin_amdgcn_ds_bpermute(adrA, _lo.y);                                      \
  int _b2 = __builtin_amdgcn_ds_bpermute(adrB, _lo.x);                                      \
  int _b3 = __builtin_amdgcn_ds_bpermute(adrB, _lo.y);                                      \
  int _hA = __builtin_amdgcn_ds_bpermute(adr0, _hlu);                                       \
  int _hB = __builtin_amdgcn_ds_bpermute(adr1, _hlu);                                       \
  int _hC = __builtin_amdgcn_ds_bpermute(adr2, _hlu);                                       \
  int _hD = __builtin_amdgcn_ds_bpermute(adr3, _hlu);                                       \
  int _w0 = (q < 2) ? _b0 : ((_hA & 0xffff) | (_hB << 16));                                 \
  int _w1 = (q < 2) ? _b1 : ((_hC & 0xffff) | (_hD << 16));                                 \
  i32x4 _bbi = { _w0, _w1, _b2, _b3 };                                                      \
  f16x8 bb = __builtin_bit_cast(f16x8, _bbi);                                               \
  f32x4 di = MFMA(Fb0, bb, MFMA(Fa0, (BA), Bi));                                            \
  f32x4 df = MFMA(Fb1, bb, MFMA(Fa1, (BA), Bf));                                            \
  f32x4 dg = MFMA(Fb2, bb, MFMA(Fa2, (BA), Bg));                                            \
  f32x4 dn = MFMA(Fb3, bb, MFMA(Fa3, (BA), Bo));                                            \
  f32x4 dl = MFMA(Fb4, bb, MFMA(Fa4, (BA), BL));                                            \
  f16x4 hv; f16 hl; CELLS5(di, df, dg, dn, dl, hv, hl)                                      \
  hvS = hv; hlS = hl;                                                                       \
  f16* dp_ = (PUB);                                                                         \
  if (dp_) { *(f16x4*)&dp_[n * 64 + SWZ1(n, (PC) + q * 4)] = hv;                            \
             dp_[n * 64 + SWZ1(n, (PC) + 16 + q)] = hl; } }

// L0 substep (LDS ring, 2 substeps/row): read row SR col-half SC
// [x(t) 8|h0(t-1) 20|pad4], write h0(t) into row DR col DC+8..27,
// publish into PUBP at col-base PC.
#define L0S(SR, SC, DR, DC, PUBP, PC) {                                                     \
  f16x8 b0 = *(const f16x8*)&zT0[SR][n * 64 + SWZ1(n, (SC) + q * 8)];                       \
  f32x4 di = MFMA(Fa0, b0, Bi), df = MFMA(Fa1, b0, Bf), dg = MFMA(Fa2, b0, Bg),             \
        dn = MFMA(Fa3, b0, Bo), dl = MFMA(Fa4, b0, BL);                                     \
  f16x4 hv; f16 hl; CELLS5(di, df, dg, dn, dl, hv, hl)                                      \
  *(f16x4*)&zT0[DR][n * 64 + SWZ1(n, (DC) + 8 + q * 4)] = hv;                               \
  zT0[DR][n * 64 + SWZ1(n, (DC) + 24 + q)] = hl;                                            \
  f16* dp_ = (PUBP);                                                                        \
  *(f16x4*)&dp_[n * 64 + SWZ1(n, (PC) + q * 4)] = hv;                                       \
  dp_[n * 64 + SWZ1(n, (PC) + 16 + q)] = hl; }

__global__ __launch_bounds__(192, 2) void lstm3_ws_kernel(
    const float* __restrict__ x,
    const float* __restrict__ Wih0, const float* __restrict__ Whh0,
    const float* __restrict__ bih0, const float* __restrict__ bhh0,
    const float* __restrict__ Wih1, const float* __restrict__ Whh1,
    const float* __restrict__ bih1, const float* __restrict__ bhh1,
    const float* __restrict__ Wih2, const float* __restrict__ Whh2,
    const float* __restrict__ bih2, const float* __restrict__ bhh2,
    const float* __restrict__ fc1w, const float* __restrict__ fc1b,
    const float* __restrict__ fc2w, const float* __restrict__ fc2b,
    float* __restrict__ out)
{
  // row r: [x(2r) 8|h0(2r-1) 20|pad4 | x(2r+1) 8|h0(2r) 20|pad4] (swizzled)
  __shared__ __align__(16) f16 zT0[4][1024];
  // [parity][rowset r]: substeps 2r (cols 0..19/16+q) and 2r+1 (cols 32..)
  __shared__ __align__(16) f16 zT1[2][4][1024];
  __shared__ __align__(16) f16 zT2[2][4][1024];
  __shared__ __align__(16) float pbuf[64];          // fc2 partials

  const int tid  = threadIdx.x;
  const int w    = tid >> 6;        // wave id = layer id
  const int lane = tid & 63;
  const int n = lane & 15;          // batch elem (N index)
  const int q = lane >> 4;          // quad

  // bpermute source-lane byte addresses (lane*4)
  const int adrA = 4 * (n + 32 * (q & 1));
  const int adrB = 4 * (n + 16 + 32 * (q & 1));
  const int adr0 = 4 * n, adr1 = 4 * (n + 16), adr2 = 4 * (n + 32), adr3 = 4 * (n + 48);

  // ---- zero z buffers (h(.)=0, c implicit 0, pads 0) ----
  {
    f16x8 zer;
#pragma unroll
    for (int j = 0; j < 8; ++j) zer[j] = (f16)0.f;
    for (int i = tid; i < 512; i += 192)  ((f16x8*)&zT0[0][0])[i] = zer;
    for (int i = tid; i < 1024; i += 192) ((f16x8*)&zT1[0][0][0])[i] = zer;
    for (int i = tid; i < 1024; i += 192) ((f16x8*)&zT2[0][0][0])[i] = zer;
  }
  __syncthreads();

  // ---- per-wave register-resident fragments (PRESCALED) ----
  auto rowmap = [](int T, int m) { return T < 4 ? T * 20 + m : (m & 3) * 20 + 16 + (m >> 2); };
  auto gscale = [](int T, int m) {
    int g = (T < 4) ? T : (m & 3);
    return (g == 2) ? -KS2 : -KS1;
  };

  f16x8 Fa0{}, Fa1{}, Fa2{}, Fa3{}, Fa4{};   // k-chunk 0 (w0: full [x|h] K)
  f16x8 Fb0{}, Fb1{}, Fb2{}, Fb3{}, Fb4{};   // k-chunk 1 (h_self; unused w0)
  f32x4 Bi{}, Bf{}, Bg{}, Bo{}, BL{};
  float c0 = 0.f, c1 = 0.f, c2 = 0.f, c3 = 0.f, cL = 0.f;
  f16x4 hvS{};                     // register h_self state (w1/w2)
  f16 hlS = (f16)0.f;

  if (w == 0) {
    auto gA0 = [&](int T) {
      int row = rowmap(T, n);
      float sc = gscale(T, n);
      f16x8 r;
#pragma unroll
      for (int j = 0; j < 8; ++j) {
        int k = q * 8 + j;
        float v = (k < 8) ? Wih0[row * 8 + k] : (k < 28 ? Whh0[row * 20 + k - 8] : 0.f);
        r[j] = (f16)(sc * v);
      }
      return r;
    };
    Fa0 = gA0(0); Fa1 = gA0(1); Fa2 = gA0(2); Fa3 = gA0(3); Fa4 = gA0(4);
    auto gB = [&](int T) {
      f32x4 r;
#pragma unroll
      for (int j = 0; j < 4; ++j) {
        int m = q * 4 + j;
        int row = rowmap(T, m);
        r[j] = gscale(T, m) * (bih0[row] + bhh0[row]);
      }
      return r;
    };
    Bi = gB(0); Bf = gB(1); Bg = gB(2); Bo = gB(3); BL = gB(4);
  } else {
    const float* Wi = (w == 1) ? Wih1 : Wih2;
    const float* Wh = (w == 1) ? Whh1 : Whh2;
    const float* bi = (w == 1) ? bih1 : bih2;
    const float* bh = (w == 1) ? bhh1 : bhh2;
    // chunk 0 covers k=0..31 = [h_in 20 | 0 pad]; chunk 1 = [h_self 20 | 0]
    auto gA = [&](int T, int c) {
      int row = rowmap(T, n);
      float sc = gscale(T, n);
      const float* W = c ? Wh : Wi;
      f16x8 r;
#pragma unroll
      for (int j = 0; j < 8; ++j) {
        int k = q * 8 + j;
        r[j] = (f16)((k < 20) ? sc * W[row * 20 + k] : 0.f);
      }
      return r;
    };
    Fa0 = gA(0, 0); Fb0 = gA(0, 1);
    Fa1 = gA(1, 0); Fb1 = gA(1, 1);
    Fa2 = gA(2, 0); Fb2 = gA(2, 1);
    Fa3 = gA(3, 0); Fb3 = gA(3, 1);
    Fa4 = gA(4, 0); Fb4 = gA(4, 1);
    auto gB = [&](int T) {
      f32x4 r;
#pragma unroll
      for (int j = 0; j < 4; ++j) {
        int m = q * 4 + j;
        int row = rowmap(T, m);
        r[j] = gscale(T, m) * (bi[row] + bh[row]);
      }
      return r;
    };
    Bi = gB(0); Bf = gB(1); Bg = gB(2); Bo = gB(3); BL = gB(4);
  }

  // x prefetch (wave0): dwordx4 = pair block of 2 timesteps.
  // pair p floats 16p..16p+15: q0,q1 -> t=2p f0..7; q2,q3 -> t=2p+1 f0..7.
  // group j = pairs 4j..4j+3 (timesteps 8j..8j+7).
  const float* xb = x + (size_t)(blockIdx.x * 16 + n) * (T_LEN * 8) + 4 * q;
  f32x4 xA{}, xB{}, xC{}, xD{};
  if (w == 0) {
    xA = *(const f32x4*)(xb);        // pair 0
    xB = *(const f32x4*)(xb + 16);   // pair 1
    xC = *(const f32x4*)(xb + 32);   // pair 2
    xD = *(const f32x4*)(xb + 48);   // pair 3
  }

  // ---- main loop: 8 timesteps per barrier ----
#pragma unroll 1
  for (int j = 0; j <= NJ; ++j) {
    asm volatile("" ::: "memory");   // pin LDS traffic in-loop (R4 fix)
    __builtin_amdgcn_s_setprio(1);   // computing waves outrank barrier-parked
    const int wp = j & 1, rp = wp ^ 1;
    if (w == 0) {
      if (j <= 41) {
        // stage x group j: pair P -> row P, col-half (q>>1) (t even/odd)
        f16x4 xh;
        xh[0] = (f16)xA[0]; xh[1] = (f16)xA[1]; xh[2] = (f16)xA[2]; xh[3] = (f16)xA[3];
        *(f16x4*)&zT0[0][n * 64 + SWZ1(n, (q >> 1) * 32 + 4 * (q & 1))] = xh;
        xh[0] = (f16)xB[0]; xh[1] = (f16)xB[1]; xh[2] = (f16)xB[2]; xh[3] = (f16)xB[3];
        *(f16x4*)&zT0[1][n * 64 + SWZ1(n, (q >> 1) * 32 + 4 * (q & 1))] = xh;
        xh[0] = (f16)xC[0]; xh[1] = (f16)xC[1]; xh[2] = (f16)xC[2]; xh[3] = (f16)xC[3];
        *(f16x4*)&zT0[2][n * 64 + SWZ1(n, (q >> 1) * 32 + 4 * (q & 1))] = xh;
        xh[0] = (f16)xD[0]; xh[1] = (f16)xD[1]; xh[2] = (f16)xD[2]; xh[3] = (f16)xD[3];
        *(f16x4*)&zT0[3][n * 64 + SWZ1(n, (q >> 1) * 32 + 4 * (q & 1))] = xh;
        // prefetch group j+1 (one full iteration of slack)
        int g = (j + 1 > 41) ? 41 : j + 1;
        xA = *(const f32x4*)(xb + (size_t)(4 * g) * 16);
        xB = *(const f32x4*)(xb + (size_t)(4 * g + 1) * 16);
        xC = *(const f32x4*)(xb + (size_t)(4 * g + 2) * 16);
        xD = *(const f32x4*)(xb + (size_t)(4 * g + 3) * 16);
        f16* p1 = &zT1[wp][0][0];
        L0S(0, 0,  0, 32, p1 + 0 * 1024, 0)    // t=8j
        L0S(0, 32, 1, 0,  p1 + 0 * 1024, 32)   // t=8j+1
        L0S(1, 0,  1, 32, p1 + 1 * 1024, 0)    // t=8j+2
        L0S(1, 32, 2, 0,  p1 + 1 * 1024, 32)   // t=8j+3
        L0S(2, 0,  2, 32, p1 + 2 * 1024, 0)    // t=8j+4
        L0S(2, 32, 3, 0,  p1 + 2 * 1024, 32)   // t=8j+5
        L0S(3, 0,  3, 32, p1 + 3 * 1024, 0)    // t=8j+6
        L0S(3, 32, 0, 0,  p1 + 3 * 1024, 32)   // t=8j+7 (h0 -> row0 half0, next iter)
      }
    } else if (w == 1) {
      if (j >= 1 && j <= 42) {
        // L1 group j-1: h_in = h0 (published last iter), h_self in registers
        f16* s1 = &zT1[rp][0][0];
        f16x8 a0 = *(const f16x8*)&s1[0 * 1024 + n * 64 + SWZ1(n, 0  + q * 8)];
        f16x8 a1 = *(const f16x8*)&s1[0 * 1024 + n * 64 + SWZ1(n, 32 + q * 8)];
        f16x8 a2 = *(const f16x8*)&s1[1 * 1024 + n * 64 + SWZ1(n, 0  + q * 8)];
        f16x8 a3 = *(const f16x8*)&s1[1 * 1024 + n * 64 + SWZ1(n, 32 + q * 8)];
        f16x8 a4 = *(const f16x8*)&s1[2 * 1024 + n * 64 + SWZ1(n, 0  + q * 8)];
        f16x8 a5 = *(const f16x8*)&s1[2 * 1024 + n * 64 + SWZ1(n, 32 + q * 8)];
        f16x8 a6 = *(const f16x8*)&s1[3 * 1024 + n * 64 + SWZ1(n, 0  + q * 8)];
        f16x8 a7 = *(const f16x8*)&s1[3 * 1024 + n * 64 + SWZ1(n, 32 + q * 8)];
        f16* p2 = &zT2[wp][0][0];
        MSTEP_REG(a0, p2 + 0 * 1024, 0)
        MSTEP_REG(a1, p2 + 0 * 1024, 32)
        MSTEP_REG(a2, p2 + 1 * 1024, 0)
        MSTEP_REG(a3, p2 + 1 * 1024, 32)
        MSTEP_REG(a4, p2 + 2 * 1024, 0)
        MSTEP_REG(a5, p2 + 2 * 1024, 32)
        MSTEP_REG(a6, p2 + 3 * 1024, 0)
        MSTEP_REG(a7, p2 + 3 * 1024, 32)
      }
    } else {
      if (j >= 2) {
        // L2 group j-2: h_in = h1, h_self in registers; no publishes
        f16* s2 = &zT2[rp][0][0];
        f16x8 a0 = *(const f16x8*)&s2[0 * 1024 + n * 64 + SWZ1(n, 0  + q * 8)];
        f16x8 a1 = *(const f16x8*)&s2[0 * 1024 + n * 64 + SWZ1(n, 32 + q * 8)];
        f16x8 a2 = *(const f16x8*)&s2[1 * 1024 + n * 64 + SWZ1(n, 0  + q * 8)];
        f16x8 a3 = *(const f16x8*)&s2[1 * 1024 + n * 64 + SWZ1(n, 32 + q * 8)];
        f16x8 a4 = *(const f16x8*)&s2[2 * 1024 + n * 64 + SWZ1(n, 0  + q * 8)];
        f16x8 a5 = *(const f16x8*)&s2[2 * 1024 + n * 64 + SWZ1(n, 32 + q * 8)];
        f16x8 a6 = *(const f16x8*)&s2[3 * 1024 + n * 64 + SWZ1(n, 0  + q * 8)];
        f16x8 a7 = *(const f16x8*)&s2[3 * 1024 + n * 64 + SWZ1(n, 32 + q * 8)];
        MSTEP_REG(a0, (f16*)nullptr, 0)
        MSTEP_REG(a1, (f16*)nullptr, 0)
        MSTEP_REG(a2, (f16*)nullptr, 0)
        MSTEP_REG(a3, (f16*)nullptr, 0)
        MSTEP_REG(a4, (f16*)nullptr, 0)
        MSTEP_REG(a5, (f16*)nullptr, 0)
        MSTEP_REG(a6, (f16*)nullptr, 0)
        MSTEP_REG(a7, (f16*)nullptr, 0)
      }
    }
    __builtin_amdgcn_s_setprio(0);
    // LDS-only barrier: cross-wave handoff needs lgkmcnt(0), NOT vmcnt(0) —
    // wave0's in-flight x loads stay outstanding across it (R9 fix).
    asm volatile("s_waitcnt lgkmcnt(0)\n\ts_barrier" ::: "memory");
  }

  // ---- FC head (wave2): final h2(335) lives in hvS/hlS registers.
  if (w == 2) {
    // park h2 in LDS (c32..51 of zT2[1][0]) so each lane can read all 20 units
    *(f16x4*)&zT2[1][0][n * 64 + SWZ1(n, 32 + q * 4)] = hvS;
    zT2[1][0][n * 64 + SWZ1(n, 48 + q)] = hlS;
    asm volatile("s_waitcnt lgkmcnt(0)" ::: "memory");
    const f16* hb = &zT2[1][0][0];
    f16x4 hv0 = *(const f16x4*)&hb[n * 64 + SWZ1(n, 32)];
    f16x4 hv1 = *(const f16x4*)&hb[n * 64 + SWZ1(n, 36)];
    f16x4 hv2 = *(const f16x4*)&hb[n * 64 + SWZ1(n, 40)];
    f16x4 hv3 = *(const f16x4*)&hb[n * 64 + SWZ1(n, 44)];
    f16x4 hv4 = *(const f16x4*)&hb[n * 64 + SWZ1(n, 48)];
    float p = 0.f;
#pragma unroll
    for (int i = 0; i < 5; ++i) {
      int d = q * 5 + i;
      const float* wr = fc1w + d * 20;
      float s = fc1b[d]
        + wr[0]  * (float)hv0[0] + wr[1]  * (float)hv0[1] + wr[2]  * (float)hv0[2] + wr[3]  * (float)hv0[3]
        + wr[4]  * (float)hv1[0] + wr[5]  * (float)hv1[1] + wr[6]  * (float)hv1[2] + wr[7]  * (float)hv1[3]
        + wr[8]  * (float)hv2[0] + wr[9]  * (float)hv2[1] + wr[10] * (float)hv2[2] + wr[11] * (float)hv2[3]
        + wr[12] * (float)hv3[0] + wr[13] * (float)hv3[1] + wr[14] * (float)hv3[2] + wr[15] * (float)hv3[3]
        + wr[16] * (float)hv4[0] + wr[17] * (float)hv4[1] + wr[18] * (float)hv4[2] + wr[19] * (float)hv4[3];
      p += fc2w[d] * fmaxf(s, 0.f);
    }
    pbuf[n * 4 + q] = p;            // wave-internal, in-order
    if (q == 0) {
      f32x4 pv = *(const f32x4*)&pbuf[n * 4];
      out[blockIdx.x * 16 + n] = pv[0] + pv[1] + pv[2] + pv[3] + fc2b[0];
    }
  }
}

extern "C" void kernel_launch(void* const* d_in, const int* in_sizes, int n_in,
                              void* d_out, int out_size, void* d_ws, size_t ws_size,
                              hipStream_t stream) {
  const float* x    = (const float*)d_in[0];
  const float* Wih0 = (const float*)d_in[1];
  const float* Whh0 = (const float*)d_in[2];
  const float* bih0 = (const float*)d_in[3];
  const float* bhh0 = (const float*)d_in[4];
  const float* Wih1 = (const float*)d_in[5];
  const float* Whh1 = (const float*)d_in[6];
  const float* bih1 = (const float*)d_in[7];
  const float* bhh1 = (const float*)d_in[8];
  const float* Wih2 = (const float*)d_in[9];
  const float* Whh2 = (const float*)d_in[10];
  const float* bih2 = (const float*)d_in[11];
  const float* bhh2 = (const float*)d_in[12];
  const float* fc1w = (const float*)d_in[13];
  const float* fc1b = (const float*)d_in[14];
  const float* fc2w = (const float*)d_in[15];
  const float* fc2b = (const float*)d_in[16];
  float* out = (float*)d_out;

  hipLaunchKernelGGL(lstm3_ws_kernel, dim3(8192 / 16), dim3(192), 0, stream,
                     x, Wih0, Whh0, bih0, bhh0,
                     Wih1, Whh1, bih1, bhh1,
                     Wih2, Whh2, bih2, bhh2,
                     fc1w, fc1b, fc2w, fc2b, out);
}

// Round 9
// 378.796 us; speedup vs baseline: 1.1474x; 1.0195x over previous
//
#include <hip/hip_runtime.h>

// 3-layer LSTM (B=8192, T=336, F=8, H=20) + FC(20->20 relu) + FC(20->1).
//
// Round 15 (on R14-null): stall-fill + issue shave. (Resubmit — previous
// bench died to container infra, not the kernel.)
//  R14 (44 barriers) == R12 (86) == 285us -> barrier convoy NOT critical;
//  wall = 2042cy/ts = 1300 issue (2 heavy waves/SIMD x ~650) + ~740 stall.
//  a) PRE/FIN SOFTWARE PIPELINE (w1/w2): substep s+1's five h_in-chunk
//     MFMAs (t_i = MFMA(Fa_i, ba, B_i)) are placed between substep s's
//     bperm issue and bb use -> independent MFMA work fills the bperm DS
//     latency + Fb shadow. Two alternating f32x4 x5 accumulator sets.
//  b) hl GATHER VIA ds_swizzle: pair hl with quad-neighbor (lane^16,
//     0x401F) then 2 bperms fetch both pairs; replaces 4 bperm + 4 packs.
//  Kept: 8 ts/barrier packed rows (R14), prescaled gates + register h_self
//  (R12), hoisted h_in reads + setprio (R11), lgkm-only barrier (R9), XOR
//  swizzle (R9), unit-major leftover tile (R10), LICM pin (R4).
//
// MFMA layouts (m89/m120-verified): A[m][k]: m=lane&15,k=(lane>>4)*8+j;
// B[k][n]: n=lane&15,k=(lane>>4)*8+j; D[m][n]: n=lane&15,m=(lane>>4)*4+reg.

#define T_LEN 336
#define NJ 43   // j=0..43; w0: group j (t=8j..8j+7, j<=41); w1: group j-1; w2: group j-2

typedef _Float16 f16;
typedef _Float16 f16x4 __attribute__((ext_vector_type(4)));
typedef _Float16 f16x8 __attribute__((ext_vector_type(8)));
typedef float f32x4 __attribute__((ext_vector_type(4)));
typedef int i32x2 __attribute__((ext_vector_type(2)));
typedef int i32x4 __attribute__((ext_vector_type(4)));

#define MFMA(a, b, c) __builtin_amdgcn_mfma_f32_16x16x32_f16((a), (b), (c), 0, 0, 0)

// 16B-slot XOR swizzle for 64-f16 (128B) rows
#define SWZ1(n, c) ((c) ^ (((n) & 7) << 3))

#define KS1 1.4426950408889634f   // log2(e)
#define KS2 2.8853900817779268f   // 2*log2(e)

// prescaled activations: y arrives as -KS1*x (sigm) / -KS2*x (tanh)
__device__ __forceinline__ float sigm_p(float y) {
  return __builtin_amdgcn_rcpf(1.0f + __builtin_amdgcn_exp2f(y));
}
__device__ __forceinline__ float tanh_p(float y) {
  return 2.0f * __builtin_amdgcn_rcpf(1.0f + __builtin_amdgcn_exp2f(y)) - 1.0f;
}
__device__ __forceinline__ float tanh_fast(float x) {   // raw arg (cell state)
  return 2.0f * __builtin_amdgcn_rcpf(1.0f + __builtin_amdgcn_exp2f(-KS2 * x)) - 1.0f;
}

// 5 in-lane cells; gate inputs arrive PRESCALED (see gA/gB loaders).
#define CELLS5(DI, DF, DG, DO, DL, HV, HL) {                                                \
  { float i_=sigm_p((DI)[0]), f_=sigm_p((DF)[0]), g_=tanh_p((DG)[0]), o_=sigm_p((DO)[0]);   \
    c0 = f_*c0 + i_*g_; (HV)[0] = (f16)(o_*tanh_fast(c0)); }                                \
  { float i_=sigm_p((DI)[1]), f_=sigm_p((DF)[1]), g_=tanh_p((DG)[1]), o_=sigm_p((DO)[1]);   \
    c1 = f_*c1 + i_*g_; (HV)[1] = (f16)(o_*tanh_fast(c1)); }                                \
  { float i_=sigm_p((DI)[2]), f_=sigm_p((DF)[2]), g_=tanh_p((DG)[2]), o_=sigm_p((DO)[2]);   \
    c2 = f_*c2 + i_*g_; (HV)[2] = (f16)(o_*tanh_fast(c2)); }                                \
  { float i_=sigm_p((DI)[3]), f_=sigm_p((DF)[3]), g_=tanh_p((DG)[3]), o_=sigm_p((DO)[3]);   \
    c3 = f_*c3 + i_*g_; (HV)[3] = (f16)(o_*tanh_fast(c3)); }                                \
  { float i_=sigm_p((DL)[0]), f_=sigm_p((DL)[1]), g_=tanh_p((DL)[2]), o_=sigm_p((DL)[3]);   \
    cL = f_*cL + i_*g_; (HL) = (f16)(o_*tanh_fast(cL)); } }

// PRE phase: 5 independent h_in-chunk MFMAs into named accumulators.
#define PRE5(BA, T0, T1, T2, T3, T4) {                                                      \
  T0 = MFMA(Fa0, (BA), Bi); T1 = MFMA(Fa1, (BA), Bf); T2 = MFMA(Fa2, (BA), Bg);             \
  T3 = MFMA(Fa3, (BA), Bo); T4 = MFMA(Fa4, (BA), BL); }

// bb rebuild from hvS/hlS: 4 hv bperms + swizzle-paired hl (2 bperms).
// lane(n,q) wants bb k=8q..8q+7 of [h_self 20 | pad12]:
//  q0: h0..7; q1: h8..15; q2: h16..19 (+x0-wt garbage); q3: x0-wt garbage.
#define BBGEN(BB) {                                                                         \
  i32x2 _lo = __builtin_bit_cast(i32x2, hvS);                                               \
  int _hlu = (int)(unsigned)__builtin_bit_cast(unsigned short, hlS);                        \
  int _b0 = __builtin_amdgcn_ds_bpermute(adrA, _lo.x);                                      \
  int _b1 = __builtin_amdgcn_ds_bpermute(adrA, _lo.y);                                      \
  int _b2 = __builtin_amdgcn_ds_bpermute(adrB, _lo.x);                                      \
  int _b3 = __builtin_amdgcn_ds_bpermute(adrB, _lo.y);                                      \
  int _sw = __builtin_amdgcn_ds_swizzle(_hlu, 0x401F);  /* lane^16: quad pair */            \
  int _pair = (_hlu & 0xffff) | (_sw << 16);            /* {hl(q), hl(q^1)} */              \
  int _hA = __builtin_amdgcn_ds_bpermute(adr0, _pair);  /* {hl0,hl1} from (n,q0) */         \
  int _hB = __builtin_amdgcn_ds_bpermute(adr2, _pair);  /* {hl2,hl3} from (n,q2) */         \
  int _w0 = (q < 2) ? _b0 : _hA;                                                            \
  int _w1 = (q < 2) ? _b1 : _hB;                                                            \
  i32x4 _bbi = { _w0, _w1, _b2, _b3 };                                                      \
  BB = __builtin_bit_cast(f16x8, _bbi); }

// FIN phase: fold h_self chunk onto PRE accumulators, cells, publish.
#define FIN5(BB, T0, T1, T2, T3, T4, PUB, PC) {                                             \
  f32x4 di = MFMA(Fb0, (BB), T0);                                                           \
  f32x4 df = MFMA(Fb1, (BB), T1);                                                           \
  f32x4 dg = MFMA(Fb2, (BB), T2);                                                           \
  f32x4 dn = MFMA(Fb3, (BB), T3);                                                           \
  f32x4 dl = MFMA(Fb4, (BB), T4);                                                           \
  f16x4 hv; f16 hl; CELLS5(di, df, dg, dn, dl, hv, hl)                                      \
  hvS = hv; hlS = hl;                                                                       \
  f16* dp_ = (PUB);                                                                         \
  if (dp_) { *(f16x4*)&dp_[n * 64 + SWZ1(n, (PC) + q * 4)] = hv;                            \
             dp_[n * 64 + SWZ1(n, (PC) + 16 + q)] = hl; } }

// L0 substep (LDS ring, 2 substeps/row): read row SR col-half SC
// [x(t) 8|h0(t-1) 20|pad4], write h0(t) into row DR col DC+8..27,
// publish into PUBP at col-base PC.
#define L0S(SR, SC, DR, DC, PUBP, PC) {                                                     \
  f16x8 b0 = *(const f16x8*)&zT0[SR][n * 64 + SWZ1(n, (SC) + q * 8)];                       \
  f32x4 di = MFMA(Fa0, b0, Bi), df = MFMA(Fa1, b0, Bf), dg = MFMA(Fa2, b0, Bg),             \
        dn = MFMA(Fa3, b0, Bo), dl = MFMA(Fa4, b0, BL);                                     \
  f16x4 hv; f16 hl; CELLS5(di, df, dg, dn, dl, hv, hl)                                      \
  *(f16x4*)&zT0[DR][n * 64 + SWZ1(n, (DC) + 8 + q * 4)] = hv;                               \
  zT0[DR][n * 64 + SWZ1(n, (DC) + 24 + q)] = hl;                                            \
  f16* dp_ = (PUBP);                                                                        \
  *(f16x4*)&dp_[n * 64 + SWZ1(n, (PC) + q * 4)] = hv;                                       \
  dp_[n * 64 + SWZ1(n, (PC) + 16 + q)] = hl; }

__global__ __launch_bounds__(192, 2) void lstm3_ws_kernel(
    const float* __restrict__ x,
    const float* __restrict__ Wih0, const float* __restrict__ Whh0,
    const float* __restrict__ bih0, const float* __restrict__ bhh0,
    const float* __restrict__ Wih1, const float* __restrict__ Whh1,
    const float* __restrict__ bih1, const float* __restrict__ bhh1,
    const float* __restrict__ Wih2, const float* __restrict__ Whh2,
    const float* __restrict__ bih2, const float* __restrict__ bhh2,
    const float* __restrict__ fc1w, const float* __restrict__ fc1b,
    const float* __restrict__ fc2w, const float* __restrict__ fc2b,
    float* __restrict__ out)
{
  // row r: [x(2r) 8|h0(2r-1) 20|pad4 | x(2r+1) 8|h0(2r) 20|pad4] (swizzled)
  __shared__ __align__(16) f16 zT0[4][1024];
  // [parity][rowset r]: substeps 2r (cols 0..) and 2r+1 (cols 32..)
  __shared__ __align__(16) f16 zT1[2][4][1024];
  __shared__ __align__(16) f16 zT2[2][4][1024];
  __shared__ __align__(16) float pbuf[64];          // fc2 partials

  const int tid  = threadIdx.x;
  const int w    = tid >> 6;        // wave id = layer id
  const int lane = tid & 63;
  const int n = lane & 15;          // batch elem (N index)
  const int q = lane >> 4;          // quad

  // bpermute source-lane byte addresses (lane*4)
  const int adrA = 4 * (n + 32 * (q & 1));
  const int adrB = 4 * (n + 16 + 32 * (q & 1));
  const int adr0 = 4 * n, adr2 = 4 * (n + 32);

  // ---- zero z buffers (h(.)=0, c implicit 0, pads 0) ----
  {
    f16x8 zer;
#pragma unroll
    for (int j = 0; j < 8; ++j) zer[j] = (f16)0.f;
    for (int i = tid; i < 512; i += 192)  ((f16x8*)&zT0[0][0])[i] = zer;
    for (int i = tid; i < 1024; i += 192) ((f16x8*)&zT1[0][0][0])[i] = zer;
    for (int i = tid; i < 1024; i += 192) ((f16x8*)&zT2[0][0][0])[i] = zer;
  }
  __syncthreads();

  // ---- per-wave register-resident fragments (PRESCALED) ----
  auto rowmap = [](int T, int m) { return T < 4 ? T * 20 + m : (m & 3) * 20 + 16 + (m >> 2); };
  auto gscale = [](int T, int m) {
    int g = (T < 4) ? T : (m & 3);
    return (g == 2) ? -KS2 : -KS1;
  };

  f16x8 Fa0{}, Fa1{}, Fa2{}, Fa3{}, Fa4{};   // k-chunk 0 (w0: full [x|h] K)
  f16x8 Fb0{}, Fb1{}, Fb2{}, Fb3{}, Fb4{};   // k-chunk 1 (h_self; unused w0)
  f32x4 Bi{}, Bf{}, Bg{}, Bo{}, BL{};
  float c0 = 0.f, c1 = 0.f, c2 = 0.f, c3 = 0.f, cL = 0.f;
  f16x4 hvS{};                     // register h_self state (w1/w2)
  f16 hlS = (f16)0.f;

  if (w == 0) {
    auto gA0 = [&](int T) {
      int row = rowmap(T, n);
      float sc = gscale(T, n);
      f16x8 r;
#pragma unroll
      for (int j = 0; j < 8; ++j) {
        int k = q * 8 + j;
        float v = (k < 8) ? Wih0[row * 8 + k] : (k < 28 ? Whh0[row * 20 + k - 8] : 0.f);
        r[j] = (f16)(sc * v);
      }
      return r;
    };
    Fa0 = gA0(0); Fa1 = gA0(1); Fa2 = gA0(2); Fa3 = gA0(3); Fa4 = gA0(4);
    auto gB = [&](int T) {
      f32x4 r;
#pragma unroll
      for (int j = 0; j < 4; ++j) {
        int m = q * 4 + j;
        int row = rowmap(T, m);
        r[j] = gscale(T, m) * (bih0[row] + bhh0[row]);
      }
      return r;
    };
    Bi = gB(0); Bf = gB(1); Bg = gB(2); Bo = gB(3); BL = gB(4);
  } else {
    const float* Wi = (w == 1) ? Wih1 : Wih2;
    const float* Wh = (w == 1) ? Whh1 : Whh2;
    const float* bi = (w == 1) ? bih1 : bih2;
    const float* bh = (w == 1) ? bhh1 : bhh2;
    // chunk 0 covers k=0..31 = [h_in 20 | 0 pad]; chunk 1 = [h_self 20 | 0]
    auto gA = [&](int T, int c) {
      int row = rowmap(T, n);
      float sc = gscale(T, n);
      const float* W = c ? Wh : Wi;
      f16x8 r;
#pragma unroll
      for (int j = 0; j < 8; ++j) {
        int k = q * 8 + j;
        r[j] = (f16)((k < 20) ? sc * W[row * 20 + k] : 0.f);
      }
      return r;
    };
    Fa0 = gA(0, 0); Fb0 = gA(0, 1);
    Fa1 = gA(1, 0); Fb1 = gA(1, 1);
    Fa2 = gA(2, 0); Fb2 = gA(2, 1);
    Fa3 = gA(3, 0); Fb3 = gA(3, 1);
    Fa4 = gA(4, 0); Fb4 = gA(4, 1);
    auto gB = [&](int T) {
      f32x4 r;
#pragma unroll
      for (int j = 0; j < 4; ++j) {
        int m = q * 4 + j;
        int row = rowmap(T, m);
        r[j] = gscale(T, m) * (bi[row] + bh[row]);
      }
      return r;
    };
    Bi = gB(0); Bf = gB(1); Bg = gB(2); Bo = gB(3); BL = gB(4);
  }

  // x prefetch (wave0): dwordx4 = pair block of 2 timesteps.
  // pair p floats 16p..16p+15: q0,q1 -> t=2p f0..7; q2,q3 -> t=2p+1 f0..7.
  // group j = pairs 4j..4j+3 (timesteps 8j..8j+7).
  const float* xb = x + (size_t)(blockIdx.x * 16 + n) * (T_LEN * 8) + 4 * q;
  f32x4 xA{}, xB{}, xC{}, xD{};
  if (w == 0) {
    xA = *(const f32x4*)(xb);        // pair 0
    xB = *(const f32x4*)(xb + 16);   // pair 1
    xC = *(const f32x4*)(xb + 32);   // pair 2
    xD = *(const f32x4*)(xb + 48);   // pair 3
  }

  // ---- main loop: 8 timesteps per barrier ----
#pragma unroll 1
  for (int j = 0; j <= NJ; ++j) {
    asm volatile("" ::: "memory");   // pin LDS traffic in-loop (R4 fix)
    __builtin_amdgcn_s_setprio(1);   // computing waves outrank barrier-parked
    const int wp = j & 1, rp = wp ^ 1;
    if (w == 0) {
      if (j <= 41) {
        // stage x group j: pair P -> row P, col-half (q>>1) (t even/odd)
        f16x4 xh;
        xh[0] = (f16)xA[0]; xh[1] = (f16)xA[1]; xh[2] = (f16)xA[2]; xh[3] = (f16)xA[3];
        *(f16x4*)&zT0[0][n * 64 + SWZ1(n, (q >> 1) * 32 + 4 * (q & 1))] = xh;
        xh[0] = (f16)xB[0]; xh[1] = (f16)xB[1]; xh[2] = (f16)xB[2]; xh[3] = (f16)xB[3];
        *(f16x4*)&zT0[1][n * 64 + SWZ1(n, (q >> 1) * 32 + 4 * (q & 1))] = xh;
        xh[0] = (f16)xC[0]; xh[1] = (f16)xC[1]; xh[2] = (f16)xC[2]; xh[3] = (f16)xC[3];
        *(f16x4*)&zT0[2][n * 64 + SWZ1(n, (q >> 1) * 32 + 4 * (q & 1))] = xh;
        xh[0] = (f16)xD[0]; xh[1] = (f16)xD[1]; xh[2] = (f16)xD[2]; xh[3] = (f16)xD[3];
        *(f16x4*)&zT0[3][n * 64 + SWZ1(n, (q >> 1) * 32 + 4 * (q & 1))] = xh;
        // prefetch group j+1 (one full iteration of slack)
        int g = (j + 1 > 41) ? 41 : j + 1;
        xA = *(const f32x4*)(xb + (size_t)(4 * g) * 16);
        xB = *(const f32x4*)(xb + (size_t)(4 * g + 1) * 16);
        xC = *(const f32x4*)(xb + (size_t)(4 * g + 2) * 16);
        xD = *(const f32x4*)(xb + (size_t)(4 * g + 3) * 16);
        f16* p1 = &zT1[wp][0][0];
        L0S(0, 0,  0, 32, p1 + 0 * 1024, 0)    // t=8j
        L0S(0, 32, 1, 0,  p1 + 0 * 1024, 32)   // t=8j+1
        L0S(1, 0,  1, 32, p1 + 1 * 1024, 0)    // t=8j+2
        L0S(1, 32, 2, 0,  p1 + 1 * 1024, 32)   // t=8j+3
        L0S(2, 0,  2, 32, p1 + 2 * 1024, 0)    // t=8j+4
        L0S(2, 32, 3, 0,  p1 + 2 * 1024, 32)   // t=8j+5
        L0S(3, 0,  3, 32, p1 + 3 * 1024, 0)    // t=8j+6
        L0S(3, 32, 0, 0,  p1 + 3 * 1024, 32)   // t=8j+7 (h0 -> row0 half0, next iter)
      }
    } else if (w == 1) {
      if (j >= 1 && j <= 42) {
        // L1 group j-1: h_in = h0 (published last iter), h_self in registers.
        // PRE/FIN pipeline: substep s+1's Fa-MFMAs fill substep s's bperm shadow.
        f16* s1 = &zT1[rp][0][0];
        f16x8 a0 = *(const f16x8*)&s1[0 * 1024 + n * 64 + SWZ1(n, 0  + q * 8)];
        f16x8 a1 = *(const f16x8*)&s1[0 * 1024 + n * 64 + SWZ1(n, 32 + q * 8)];
        f16x8 a2 = *(const f16x8*)&s1[1 * 1024 + n * 64 + SWZ1(n, 0  + q * 8)];
        f16x8 a3 = *(const f16x8*)&s1[1 * 1024 + n * 64 + SWZ1(n, 32 + q * 8)];
        f16x8 a4 = *(const f16x8*)&s1[2 * 1024 + n * 64 + SWZ1(n, 0  + q * 8)];
        f16x8 a5 = *(const f16x8*)&s1[2 * 1024 + n * 64 + SWZ1(n, 32 + q * 8)];
        f16x8 a6 = *(const f16x8*)&s1[3 * 1024 + n * 64 + SWZ1(n, 0  + q * 8)];
        f16x8 a7 = *(const f16x8*)&s1[3 * 1024 + n * 64 + SWZ1(n, 32 + q * 8)];
        f16* p2 = &zT2[wp][0][0];
        f32x4 tA0, tA1, tA2, tA3, tA4, tB0, tB1, tB2, tB3, tB4;
        f16x8 bb;
        PRE5(a0, tA0, tA1, tA2, tA3, tA4)
        BBGEN(bb) PRE5(a1, tB0, tB1, tB2, tB3, tB4) FIN5(bb, tA0, tA1, tA2, tA3, tA4, p2 + 0 * 1024, 0)
        BBGEN(bb) PRE5(a2, tA0, tA1, tA2, tA3, tA4) FIN5(bb, tB0, tB1, tB2, tB3, tB4, p2 + 0 * 1024, 32)
        BBGEN(bb) PRE5(a3, tB0, tB1, tB2, tB3, tB4) FIN5(bb, tA0, tA1, tA2, tA3, tA4, p2 + 1 * 1024, 0)
        BBGEN(bb) PRE5(a4, tA0, tA1, tA2, tA3, tA4) FIN5(bb, tB0, tB1, tB2, tB3, tB4, p2 + 1 * 1024, 32)
        BBGEN(bb) PRE5(a5, tB0, tB1, tB2, tB3, tB4) FIN5(bb, tA0, tA1, tA2, tA3, tA4, p2 + 2 * 1024, 0)
        BBGEN(bb) PRE5(a6, tA0, tA1, tA2, tA3, tA4) FIN5(bb, tB0, tB1, tB2, tB3, tB4, p2 + 2 * 1024, 32)
        BBGEN(bb) PRE5(a7, tB0, tB1, tB2, tB3, tB4) FIN5(bb, tA0, tA1, tA2, tA3, tA4, p2 + 3 * 1024, 0)
        BBGEN(bb)                                   FIN5(bb, tB0, tB1, tB2, tB3, tB4, p2 + 3 * 1024, 32)
      }
    } else {
      if (j >= 2) {
        // L2 group j-2: h_in = h1, h_self in registers; no publishes
        f16* s2 = &zT2[rp][0][0];
        f16x8 a0 = *(const f16x8*)&s2[0 * 1024 + n * 64 + SWZ1(n, 0  + q * 8)];
        f16x8 a1 = *(const f16x8*)&s2[0 * 1024 + n * 64 + SWZ1(n, 32 + q * 8)];
        f16x8 a2 = *(const f16x8*)&s2[1 * 1024 + n * 64 + SWZ1(n, 0  + q * 8)];
        f16x8 a3 = *(const f16x8*)&s2[1 * 1024 + n * 64 + SWZ1(n, 32 + q * 8)];
        f16x8 a4 = *(const f16x8*)&s2[2 * 1024 + n * 64 + SWZ1(n, 0  + q * 8)];
        f16x8 a5 = *(const f16x8*)&s2[2 * 1024 + n * 64 + SWZ1(n, 32 + q * 8)];
        f16x8 a6 = *(const f16x8*)&s2[3 * 1024 + n * 64 + SWZ1(n, 0  + q * 8)];
        f16x8 a7 = *(const f16x8*)&s2[3 * 1024 + n * 64 + SWZ1(n, 32 + q * 8)];
        f32x4 tA0, tA1, tA2, tA3, tA4, tB0, tB1, tB2, tB3, tB4;
        f16x8 bb;
        PRE5(a0, tA0, tA1, tA2, tA3, tA4)
        BBGEN(bb) PRE5(a1, tB0, tB1, tB2, tB3, tB4) FIN5(bb, tA0, tA1, tA2, tA3, tA4, (f16*)nullptr, 0)
        BBGEN(bb) PRE5(a2, tA0, tA1, tA2, tA3, tA4) FIN5(bb, tB0, tB1, tB2, tB3, tB4, (f16*)nullptr, 0)
        BBGEN(bb) PRE5(a3, tB0, tB1, tB2, tB3, tB4) FIN5(bb, tA0, tA1, tA2, tA3, tA4, (f16*)nullptr, 0)
        BBGEN(bb) PRE5(a4, tA0, tA1, tA2, tA3, tA4) FIN5(bb, tB0, tB1, tB2, tB3, tB4, (f16*)nullptr, 0)
        BBGEN(bb) PRE5(a5, tB0, tB1, tB2, tB3, tB4) FIN5(bb, tA0, tA1, tA2, tA3, tA4, (f16*)nullptr, 0)
        BBGEN(bb) PRE5(a6, tA0, tA1, tA2, tA3, tA4) FIN5(bb, tB0, tB1, tB2, tB3, tB4, (f16*)nullptr, 0)
        BBGEN(bb) PRE5(a7, tB0, tB1, tB2, tB3, tB4) FIN5(bb, tA0, tA1, tA2, tA3, tA4, (f16*)nullptr, 0)
        BBGEN(bb)                                   FIN5(bb, tB0, tB1, tB2, tB3, tB4, (f16*)nullptr, 0)
      }
    }
    __builtin_amdgcn_s_setprio(0);
    // LDS-only barrier: cross-wave handoff needs lgkmcnt(0), NOT vmcnt(0) —
    // wave0's in-flight x loads stay outstanding across it (R9 fix).
    asm volatile("s_waitcnt lgkmcnt(0)\n\ts_barrier" ::: "memory");
  }

  // ---- FC head (wave2): final h2(335) lives in hvS/hlS registers.
  if (w == 2) {
    // park h2 in LDS (c32..51 of zT2[1][0]) so each lane can read all 20 units
    *(f16x4*)&zT2[1][0][n * 64 + SWZ1(n, 32 + q * 4)] = hvS;
    zT2[1][0][n * 64 + SWZ1(n, 48 + q)] = hlS;
    asm volatile("s_waitcnt lgkmcnt(0)" ::: "memory");
    const f16* hb = &zT2[1][0][0];
    f16x4 hv0 = *(const f16x4*)&hb[n * 64 + SWZ1(n, 32)];
    f16x4 hv1 = *(const f16x4*)&hb[n * 64 + SWZ1(n, 36)];
    f16x4 hv2 = *(const f16x4*)&hb[n * 64 + SWZ1(n, 40)];
    f16x4 hv3 = *(const f16x4*)&hb[n * 64 + SWZ1(n, 44)];
    f16x4 hv4 = *(const f16x4*)&hb[n * 64 + SWZ1(n, 48)];
    float p = 0.f;
#pragma unroll
    for (int i = 0; i < 5; ++i) {
      int d = q * 5 + i;
      const float* wr = fc1w + d * 20;
      float s = fc1b[d]
        + wr[0]  * (float)hv0[0] + wr[1]  * (float)hv0[1] + wr[2]  * (float)hv0[2] + wr[3]  * (float)hv0[3]
        + wr[4]  * (float)hv1[0] + wr[5]  * (float)hv1[1] + wr[6]  * (float)hv1[2] + wr[7]  * (float)hv1[3]
        + wr[8]  * (float)hv2[0] + wr[9]  * (float)hv2[1] + wr[10] * (float)hv2[2] + wr[11] * (float)hv2[3]
        + wr[12] * (float)hv3[0] + wr[13] * (float)hv3[1] + wr[14] * (float)hv3[2] + wr[15] * (float)hv3[3]
        + wr[16] * (float)hv4[0] + wr[17] * (float)hv4[1] + wr[18] * (float)hv4[2] + wr[19] * (float)hv4[3];
      p += fc2w[d] * fmaxf(s, 0.f);
    }
    pbuf[n * 4 + q] = p;            // wave-internal, in-order
    if (q == 0) {
      f32x4 pv = *(const f32x4*)&pbuf[n * 4];
      out[blockIdx.x * 16 + n] = pv[0] + pv[1] + pv[2] + pv[3] + fc2b[0];
    }
  }
}

extern "C" void kernel_launch(void* const* d_in, const int* in_sizes, int n_in,
                              void* d_out, int out_size, void* d_ws, size_t ws_size,
                              hipStream_t stream) {
  const float* x    = (const float*)d_in[0];
  const float* Wih0 = (const float*)d_in[1];
  const float* Whh0 = (const float*)d_in[2];
  const float* bih0 = (const float*)d_in[3];
  const float* bhh0 = (const float*)d_in[4];
  const float* Wih1 = (const float*)d_in[5];
  const float* Whh1 = (const float*)d_in[6];
  const float* bih1 = (const float*)d_in[7];
  const float* bhh1 = (const float*)d_in[8];
  const float* Wih2 = (const float*)d_in[9];
  const float* Whh2 = (const float*)d_in[10];
  const float* bih2 = (const float*)d_in[11];
  const float* bhh2 = (const float*)d_in[12];
  const float* fc1w = (const float*)d_in[13];
  const float* fc1b = (const float*)d_in[14];
  const float* fc2w = (const float*)d_in[15];
  const float* fc2b = (const float*)d_in[16];
  float* out = (float*)d_out;

  hipLaunchKernelGGL(lstm3_ws_kernel, dim3(8192 / 16), dim3(192), 0, stream,
                     x, Wih0, Whh0, bih0, bhh0,
                     Wih1, Whh1, bih1, bhh1,
                     Wih2, Whh2, bih2, bhh2,
                     fc1w, fc1b, fc2w, fc2b, out);
}